// Round 14
// baseline (99.849 us; speedup 1.0000x reference)
//
#include <hip/hip_runtime.h>

#define N_   32
#define C_   3
#define T_   300
#define V_   25
#define OUT_ 96
#define ROWP 28              // padded row (float4-aligned)
#define NCH  60              // partial records per n (15 chunks x 4 waves)
#define TT2  20              // t's per k_out block (500 j per block)
#define SEL  (3*V_*V_)       // 1875 floats per sum record

using half8   = __attribute__((ext_vector_type(8))) _Float16;
using floatx4 = __attribute__((ext_vector_type(4))) float;

// ---------------------------------------------------------------------------
// K1 (MFMA): round-11/13 version byte-identical. Launched 4x THIS ROUND
// (idempotent) purely to measure its duration: dur - 57.4 = 3 * t(k_powsum).
// ---------------------------------------------------------------------------
__global__ __launch_bounds__(256) void k_powsum(const float* __restrict__ xx,
                                                float* __restrict__ partial) {
    const int n = blockIdx.x, chunk = blockIdx.y;   // 15 chunks x 20 t
    const int tid  = threadIdx.x;
    const int wid  = tid >> 6;
    const int lane = tid & 63;
    const int r0   = lane & 15;
    const int kb   = (lane >> 4) * 8;

    __shared__ __align__(16) float xst[4][3][32];
    __shared__ __align__(16) float a2b[4][32][36];

    half8 I0 = {}, I1 = {};
    #pragma unroll
    for (int j = 0; j < 8; ++j) {
        if (kb + j == r0)      I0[j] = (_Float16)1.0f;
        if (kb + j == 16 + r0) I1[j] = (_Float16)1.0f;
    }

    floatx4 acc[3][4];
    #pragma unroll
    for (int s = 0; s < 3; ++s)
        #pragma unroll
        for (int q = 0; q < 4; ++q)
            #pragma unroll
            for (int r = 0; r < 4; ++r) acc[s][q][r] = 0.f;

    const float* xxn = xx + (size_t)n * C_*T_*V_;
    const bool rowOK1 = (r0 < 9);

    for (int tt = 0; tt < 5; ++tt) {
        const int t = chunk*20 + wid*5 + tt;
        {
            const int i0 = lane;
            if (i0 < 75) xst[wid][i0/25][i0%25] = xxn[(i0/25)*(T_*V_) + t*V_ + (i0%25)];
            const int i1 = 64 + lane;
            if (lane < 11) xst[wid][i1/25][i1%25] = xxn[(i1/25)*(T_*V_) + t*V_ + (i1%25)];
        }
        __syncthreads();

        float xr0c[3], xr1c[3], xk[3][8];
        #pragma unroll
        for (int c = 0; c < 3; ++c) {
            xr0c[c] = xst[wid][c][r0];
            xr1c[c] = xst[wid][c][16 + r0];
            const float4 k0 = *(const float4*)&xst[wid][c][kb];
            const float4 k1 = *(const float4*)&xst[wid][c][kb + 4];
            xk[c][0]=k0.x; xk[c][1]=k0.y; xk[c][2]=k0.z; xk[c][3]=k0.w;
            xk[c][4]=k1.x; xk[c][5]=k1.y; xk[c][6]=k1.z; xk[c][7]=k1.w;
        }
        half8 F0, F1;
        #pragma unroll
        for (int j = 0; j < 8; ++j) {
            const int  kk  = kb + j;
            const bool kOK = (kk < 25);
            float d0 = xr0c[0]-xk[0][j], d1 = xr0c[1]-xk[1][j], d2 = xr0c[2]-xk[2][j];
            const float a0 = __expf(-(d0*d0 + d1*d1 + d2*d2));
            F0[j] = kOK ? (_Float16)a0 : (_Float16)0.f;
            float e0 = xr1c[0]-xk[0][j], e1 = xr1c[1]-xk[1][j], e2 = xr1c[2]-xk[2][j];
            const float a1 = __expf(-(e0*e0 + e1*e1 + e2*e2));
            F1[j] = (kOK && rowOK1) ? (_Float16)a1 : (_Float16)0.f;
        }

        const floatx4 z = {0.f, 0.f, 0.f, 0.f};
        floatx4 d2q[4];
        d2q[0] = __builtin_amdgcn_mfma_f32_16x16x32_f16(F0, F0, z, 0, 0, 0);
        d2q[1] = __builtin_amdgcn_mfma_f32_16x16x32_f16(F0, F1, z, 0, 0, 0);
        d2q[2] = __builtin_amdgcn_mfma_f32_16x16x32_f16(F1, F0, z, 0, 0, 0);
        d2q[3] = __builtin_amdgcn_mfma_f32_16x16x32_f16(F1, F1, z, 0, 0, 0);
        acc[0][0] = __builtin_amdgcn_mfma_f32_16x16x32_f16(I0, F0, acc[0][0], 0, 0, 0);
        acc[0][1] = __builtin_amdgcn_mfma_f32_16x16x32_f16(I0, F1, acc[0][1], 0, 0, 0);
        acc[0][2] = __builtin_amdgcn_mfma_f32_16x16x32_f16(I1, F0, acc[0][2], 0, 0, 0);
        acc[0][3] = __builtin_amdgcn_mfma_f32_16x16x32_f16(I1, F1, acc[0][3], 0, 0, 0);
        const int rbase = (lane >> 4) * 4;
        #pragma unroll
        for (int q = 0; q < 4; ++q) {
            #pragma unroll
            for (int r = 0; r < 4; ++r) acc[1][q][r] += d2q[q][r];
            const int RB = 16*(q>>1) + rbase, CC = 16*(q&1) + r0;
            #pragma unroll
            for (int r = 0; r < 4; ++r) a2b[wid][RB + r][CC] = d2q[q][r];
        }
        __syncthreads();

        const float4 m0 = *(const float4*)&a2b[wid][r0][kb];
        const float4 m1 = *(const float4*)&a2b[wid][r0][kb + 4];
        const float4 m2 = *(const float4*)&a2b[wid][16 + r0][kb];
        const float4 m3 = *(const float4*)&a2b[wid][16 + r0][kb + 4];
        half8 FA0, FA1;
        FA0[0]=(_Float16)m0.x; FA0[1]=(_Float16)m0.y; FA0[2]=(_Float16)m0.z; FA0[3]=(_Float16)m0.w;
        FA0[4]=(_Float16)m1.x; FA0[5]=(_Float16)m1.y; FA0[6]=(_Float16)m1.z; FA0[7]=(_Float16)m1.w;
        FA1[0]=(_Float16)m2.x; FA1[1]=(_Float16)m2.y; FA1[2]=(_Float16)m2.z; FA1[3]=(_Float16)m2.w;
        FA1[4]=(_Float16)m3.x; FA1[5]=(_Float16)m3.y; FA1[6]=(_Float16)m3.z; FA1[7]=(_Float16)m3.w;
        acc[2][0] = __builtin_amdgcn_mfma_f32_16x16x32_f16(FA0, F0, acc[2][0], 0, 0, 0);
        acc[2][1] = __builtin_amdgcn_mfma_f32_16x16x32_f16(FA0, F1, acc[2][1], 0, 0, 0);
        acc[2][2] = __builtin_amdgcn_mfma_f32_16x16x32_f16(FA1, F0, acc[2][2], 0, 0, 0);
        acc[2][3] = __builtin_amdgcn_mfma_f32_16x16x32_f16(FA1, F1, acc[2][3], 0, 0, 0);
        __syncthreads();
    }

    float* pb = partial + ((size_t)n*NCH + chunk*4 + wid) * SEL;
    const int rbase = (lane >> 4) * 4;
    #pragma unroll
    for (int s = 0; s < 3; ++s) {
        #pragma unroll
        for (int q = 0; q < 4; ++q) {
            const int RB = 16*(q>>1) + rbase, CC = 16*(q&1) + r0;
            #pragma unroll
            for (int r = 0; r < 4; ++r) a2b[wid][RB + r][CC] = acc[s][q][r];
        }
        __syncthreads();
        for (int i = lane; i < V_*V_; i += 64)
            pb[s*V_*V_ + i] = a2b[wid][i/V_][i%V_];
        __syncthreads();
    }
}

// ---------------------------------------------------------------------------
// K1b: byte-identical r13.
// ---------------------------------------------------------------------------
__global__ __launch_bounds__(256) void k_reduce(const float* __restrict__ partial,
                                                float* __restrict__ Ssum) {
    const int g = blockIdx.x*256 + threadIdx.x;
    if (g >= N_*SEL) return;
    const int n = g / SEL, j = g % SEL;
    const float* p = partial + (size_t)n*NCH*SEL + j;
    float s = 0.f;
    #pragma unroll
    for (int c = 0; c < NCH; ++c) s += p[(size_t)c*SEL];
    Ssum[g] = s;
}

// ---------------------------------------------------------------------------
// K2 v10: byte-identical r13 (j-pair, float2 stores).
// ---------------------------------------------------------------------------
__global__ __launch_bounds__(256) void k_out(const float* __restrict__ x,
                                             const float* __restrict__ Ssum,
                                             const float* __restrict__ W,
                                             const float* __restrict__ b,
                                             const float* __restrict__ gamma,
                                             const float* __restrict__ beta,
                                             float* __restrict__ out) {
    const int n = blockIdx.x, tile = blockIdx.y;  // 15 tiles x 20 t
    const int tid = threadIdx.x;

    __shared__ __align__(16) float S_l[3*V_*ROWP];     // 2100
    __shared__ __align__(16) float xsh[TT2*C_*ROWP];   // 1680
    __shared__ __align__(16) float Wl[OUT_*12];        // 1152
    __shared__ __align__(8)  float2 so[OUT_];          // (scl, off) packed

    const float* xn = x + (size_t)n * C_*T_*V_;
    const int t0 = tile * TT2;
    const float inv_bn = rsqrtf(1.0f + 1e-5f);

    for (int i = tid; i < 3*V_*ROWP; i += 256) {
        const int s = i/(V_*ROWP), r = i%(V_*ROWP), v = r/ROWP, u = r%ROWP;
        S_l[i] = (u < V_) ? Ssum[(size_t)n*SEL + s*V_*V_ + v*V_ + u] : 0.f;
    }
    for (int i = tid; i < TT2*C_*ROWP; i += 256) {
        const int tt = i/(C_*ROWP), r = i%(C_*ROWP), c = r/ROWP, u = r%ROWP;
        xsh[i] = (u < V_) ? xn[c*(T_*V_) + (t0+tt)*V_ + u] : 0.f;
    }
    for (int i = tid; i < OUT_*12; i += 256) Wl[i] = W[i];
    if (tid < OUT_) {
        const float sc = gamma[tid] * inv_bn;
        so[tid] = make_float2(sc, b[tid]*sc + beta[tid]);
    }
    __syncthreads();

    if (tid < TT2*V_/2) {
        const int j0 = 2*tid, j1 = 2*tid + 1;
        const int tt0 = j0 / V_, iv0 = j0 % V_;
        const int tt1 = j1 / V_, iv1 = j1 % V_;
        const float* xb0 = &xsh[tt0*C_*ROWP];
        const float* xb1 = &xsh[tt1*C_*ROWP];

        float agg0[12], agg1[12];
        agg0[0] = (float)T_ * xb0[0*ROWP + iv0];
        agg0[1] = (float)T_ * xb0[1*ROWP + iv0];
        agg0[2] = (float)T_ * xb0[2*ROWP + iv0];
        agg1[0] = (float)T_ * xb1[0*ROWP + iv1];
        agg1[1] = (float)T_ * xb1[1*ROWP + iv1];
        agg1[2] = (float)T_ * xb1[2*ROWP + iv1];
        #pragma unroll
        for (int k = 3; k < 12; ++k) { agg0[k] = 0.f; agg1[k] = 0.f; }

        const float* Sr[3] = { &S_l[0*V_*ROWP], &S_l[1*V_*ROWP], &S_l[2*V_*ROWP] };
        #pragma unroll
        for (int u4 = 0; u4 < ROWP; u4 += 4) {
            const float4 p0 = *(const float4*)&xb0[0*ROWP + u4];
            const float4 p1 = *(const float4*)&xb0[1*ROWP + u4];
            const float4 p2 = *(const float4*)&xb0[2*ROWP + u4];
            const float4 q0 = *(const float4*)&xb1[0*ROWP + u4];
            const float4 q1 = *(const float4*)&xb1[1*ROWP + u4];
            const float4 q2 = *(const float4*)&xb1[2*ROWP + u4];
            #pragma unroll
            for (int s = 0; s < 3; ++s) {
                const float4 sa = *(const float4*)&Sr[s][iv0*ROWP + u4];
                const float4 sb = *(const float4*)&Sr[s][iv1*ROWP + u4];
                agg0[3*s+3] += sa.x*p0.x + sa.y*p0.y + sa.z*p0.z + sa.w*p0.w;
                agg0[3*s+4] += sa.x*p1.x + sa.y*p1.y + sa.z*p1.z + sa.w*p1.w;
                agg0[3*s+5] += sa.x*p2.x + sa.y*p2.y + sa.z*p2.z + sa.w*p2.w;
                agg1[3*s+3] += sb.x*q0.x + sb.y*q0.y + sb.z*q0.z + sb.w*q0.w;
                agg1[3*s+4] += sb.x*q1.x + sb.y*q1.y + sb.z*q1.z + sb.w*q1.w;
                agg1[3*s+5] += sb.x*q2.x + sb.y*q2.y + sb.z*q2.z + sb.w*q2.w;
            }
        }

        float* on = out + (size_t)n*(size_t)OUT_*T_*V_ + t0*V_ + j0;
        #pragma unroll 4
        for (int o = 0; o < OUT_; ++o) {
            const float4 w0 = *(const float4*)&Wl[o*12];
            const float4 w1 = *(const float4*)&Wl[o*12+4];
            const float4 w2 = *(const float4*)&Wl[o*12+8];
            const float2 s2 = so[o];
            float a0 = w0.x*agg0[0] + w0.y*agg0[1] + w0.z*agg0[2] + w0.w*agg0[3]
                     + w1.x*agg0[4] + w1.y*agg0[5] + w1.z*agg0[6] + w1.w*agg0[7]
                     + w2.x*agg0[8] + w2.y*agg0[9] + w2.z*agg0[10]+ w2.w*agg0[11];
            float a1 = w0.x*agg1[0] + w0.y*agg1[1] + w0.z*agg1[2] + w0.w*agg1[3]
                     + w1.x*agg1[4] + w1.y*agg1[5] + w1.z*agg1[6] + w1.w*agg1[7]
                     + w2.x*agg1[8] + w2.y*agg1[9] + w2.z*agg1[10]+ w2.w*agg1[11];
            float2 r;
            r.x = fmaxf(a0*s2.x + s2.y, 0.f);
            r.y = fmaxf(a1*s2.x + s2.y, 0.f);
            *(float2*)&on[(size_t)o*(T_*V_)] = r;
        }
    }
}

extern "C" void kernel_launch(void* const* d_in, const int* in_sizes, int n_in,
                              void* d_out, int out_size, void* d_ws, size_t ws_size,
                              hipStream_t stream) {
    const float* x     = (const float*)d_in[0];
    const float* xx    = (const float*)d_in[1];
    const float* W     = (const float*)d_in[2];
    const float* b     = (const float*)d_in[3];
    const float* gamma = (const float*)d_in[4];
    const float* beta  = (const float*)d_in[5];
    float* out  = (float*)d_out;

    float* Ssum    = (float*)d_ws;                  // 240 KB
    float* partial = (float*)d_ws + (size_t)N_*SEL; // 14.4 MB (60 recs/n)

    // MEASUREMENT ROUND: k_powsum launched 4x (idempotent, identical writes).
    // dur_us - 57.4 ≈ 3 * t(k_powsum). Intentional, expected regression.
    k_powsum<<<dim3(N_, 15), 256, 0, stream>>>(xx, partial);
    k_powsum<<<dim3(N_, 15), 256, 0, stream>>>(xx, partial);
    k_powsum<<<dim3(N_, 15), 256, 0, stream>>>(xx, partial);
    k_powsum<<<dim3(N_, 15), 256, 0, stream>>>(xx, partial);
    k_reduce<<<(N_*SEL + 255)/256, 256, 0, stream>>>(partial, Ssum);
    k_out   <<<dim3(N_, T_/TT2), 256, 0, stream>>>(x, Ssum, W, b, gamma, beta, out);
}

// Round 15
// 76.988 us; speedup vs baseline: 1.2970x; 1.2970x over previous
//
#include <hip/hip_runtime.h>

#define N_   32
#define C_   3
#define T_   300
#define V_   25
#define OUT_ 96
#define ROWP 28              // padded row (float4-aligned)
#define NCH  60              // partial records per n (15 chunks x 4 waves)
#define TT2  20              // t's per k_out block (500 j per block)
#define SEL  (3*V_*V_)       // 1875 floats per sum record

using half8   = __attribute__((ext_vector_type(8))) _Float16;
using floatx4 = __attribute__((ext_vector_type(4))) float;

// ---------------------------------------------------------------------------
// K1 (MFMA): round-11/13 version byte-identical. Measured: 14.2us (r14 4x).
// ---------------------------------------------------------------------------
__global__ __launch_bounds__(256) void k_powsum(const float* __restrict__ xx,
                                                float* __restrict__ partial) {
    const int n = blockIdx.x, chunk = blockIdx.y;   // 15 chunks x 20 t
    const int tid  = threadIdx.x;
    const int wid  = tid >> 6;
    const int lane = tid & 63;
    const int r0   = lane & 15;
    const int kb   = (lane >> 4) * 8;

    __shared__ __align__(16) float xst[4][3][32];
    __shared__ __align__(16) float a2b[4][32][36];

    half8 I0 = {}, I1 = {};
    #pragma unroll
    for (int j = 0; j < 8; ++j) {
        if (kb + j == r0)      I0[j] = (_Float16)1.0f;
        if (kb + j == 16 + r0) I1[j] = (_Float16)1.0f;
    }

    floatx4 acc[3][4];
    #pragma unroll
    for (int s = 0; s < 3; ++s)
        #pragma unroll
        for (int q = 0; q < 4; ++q)
            #pragma unroll
            for (int r = 0; r < 4; ++r) acc[s][q][r] = 0.f;

    const float* xxn = xx + (size_t)n * C_*T_*V_;
    const bool rowOK1 = (r0 < 9);

    for (int tt = 0; tt < 5; ++tt) {
        const int t = chunk*20 + wid*5 + tt;
        {
            const int i0 = lane;
            if (i0 < 75) xst[wid][i0/25][i0%25] = xxn[(i0/25)*(T_*V_) + t*V_ + (i0%25)];
            const int i1 = 64 + lane;
            if (lane < 11) xst[wid][i1/25][i1%25] = xxn[(i1/25)*(T_*V_) + t*V_ + (i1%25)];
        }
        __syncthreads();

        float xr0c[3], xr1c[3], xk[3][8];
        #pragma unroll
        for (int c = 0; c < 3; ++c) {
            xr0c[c] = xst[wid][c][r0];
            xr1c[c] = xst[wid][c][16 + r0];
            const float4 k0 = *(const float4*)&xst[wid][c][kb];
            const float4 k1 = *(const float4*)&xst[wid][c][kb + 4];
            xk[c][0]=k0.x; xk[c][1]=k0.y; xk[c][2]=k0.z; xk[c][3]=k0.w;
            xk[c][4]=k1.x; xk[c][5]=k1.y; xk[c][6]=k1.z; xk[c][7]=k1.w;
        }
        half8 F0, F1;
        #pragma unroll
        for (int j = 0; j < 8; ++j) {
            const int  kk  = kb + j;
            const bool kOK = (kk < 25);
            float d0 = xr0c[0]-xk[0][j], d1 = xr0c[1]-xk[1][j], d2 = xr0c[2]-xk[2][j];
            const float a0 = __expf(-(d0*d0 + d1*d1 + d2*d2));
            F0[j] = kOK ? (_Float16)a0 : (_Float16)0.f;
            float e0 = xr1c[0]-xk[0][j], e1 = xr1c[1]-xk[1][j], e2 = xr1c[2]-xk[2][j];
            const float a1 = __expf(-(e0*e0 + e1*e1 + e2*e2));
            F1[j] = (kOK && rowOK1) ? (_Float16)a1 : (_Float16)0.f;
        }

        const floatx4 z = {0.f, 0.f, 0.f, 0.f};
        floatx4 d2q[4];
        d2q[0] = __builtin_amdgcn_mfma_f32_16x16x32_f16(F0, F0, z, 0, 0, 0);
        d2q[1] = __builtin_amdgcn_mfma_f32_16x16x32_f16(F0, F1, z, 0, 0, 0);
        d2q[2] = __builtin_amdgcn_mfma_f32_16x16x32_f16(F1, F0, z, 0, 0, 0);
        d2q[3] = __builtin_amdgcn_mfma_f32_16x16x32_f16(F1, F1, z, 0, 0, 0);
        acc[0][0] = __builtin_amdgcn_mfma_f32_16x16x32_f16(I0, F0, acc[0][0], 0, 0, 0);
        acc[0][1] = __builtin_amdgcn_mfma_f32_16x16x32_f16(I0, F1, acc[0][1], 0, 0, 0);
        acc[0][2] = __builtin_amdgcn_mfma_f32_16x16x32_f16(I1, F0, acc[0][2], 0, 0, 0);
        acc[0][3] = __builtin_amdgcn_mfma_f32_16x16x32_f16(I1, F1, acc[0][3], 0, 0, 0);
        const int rbase = (lane >> 4) * 4;
        #pragma unroll
        for (int q = 0; q < 4; ++q) {
            #pragma unroll
            for (int r = 0; r < 4; ++r) acc[1][q][r] += d2q[q][r];
            const int RB = 16*(q>>1) + rbase, CC = 16*(q&1) + r0;
            #pragma unroll
            for (int r = 0; r < 4; ++r) a2b[wid][RB + r][CC] = d2q[q][r];
        }
        __syncthreads();

        const float4 m0 = *(const float4*)&a2b[wid][r0][kb];
        const float4 m1 = *(const float4*)&a2b[wid][r0][kb + 4];
        const float4 m2 = *(const float4*)&a2b[wid][16 + r0][kb];
        const float4 m3 = *(const float4*)&a2b[wid][16 + r0][kb + 4];
        half8 FA0, FA1;
        FA0[0]=(_Float16)m0.x; FA0[1]=(_Float16)m0.y; FA0[2]=(_Float16)m0.z; FA0[3]=(_Float16)m0.w;
        FA0[4]=(_Float16)m1.x; FA0[5]=(_Float16)m1.y; FA0[6]=(_Float16)m1.z; FA0[7]=(_Float16)m1.w;
        FA1[0]=(_Float16)m2.x; FA1[1]=(_Float16)m2.y; FA1[2]=(_Float16)m2.z; FA1[3]=(_Float16)m2.w;
        FA1[4]=(_Float16)m3.x; FA1[5]=(_Float16)m3.y; FA1[6]=(_Float16)m3.z; FA1[7]=(_Float16)m3.w;
        acc[2][0] = __builtin_amdgcn_mfma_f32_16x16x32_f16(FA0, F0, acc[2][0], 0, 0, 0);
        acc[2][1] = __builtin_amdgcn_mfma_f32_16x16x32_f16(FA0, F1, acc[2][1], 0, 0, 0);
        acc[2][2] = __builtin_amdgcn_mfma_f32_16x16x32_f16(FA1, F0, acc[2][2], 0, 0, 0);
        acc[2][3] = __builtin_amdgcn_mfma_f32_16x16x32_f16(FA1, F1, acc[2][3], 0, 0, 0);
        __syncthreads();
    }

    float* pb = partial + ((size_t)n*NCH + chunk*4 + wid) * SEL;
    const int rbase = (lane >> 4) * 4;
    #pragma unroll
    for (int s = 0; s < 3; ++s) {
        #pragma unroll
        for (int q = 0; q < 4; ++q) {
            const int RB = 16*(q>>1) + rbase, CC = 16*(q&1) + r0;
            #pragma unroll
            for (int r = 0; r < 4; ++r) a2b[wid][RB + r][CC] = acc[s][q][r];
        }
        __syncthreads();
        for (int i = lane; i < V_*V_; i += 64)
            pb[s*V_*V_ + i] = a2b[wid][i/V_][i%V_];
        __syncthreads();
    }
}

// ---------------------------------------------------------------------------
// K1b: byte-identical r13.
// ---------------------------------------------------------------------------
__global__ __launch_bounds__(256) void k_reduce(const float* __restrict__ partial,
                                                float* __restrict__ Ssum) {
    const int g = blockIdx.x*256 + threadIdx.x;
    if (g >= N_*SEL) return;
    const int n = g / SEL, j = g % SEL;
    const float* p = partial + (size_t)n*NCH*SEL + j;
    float s = 0.f;
    #pragma unroll
    for (int c = 0; c < NCH; ++c) s += p[(size_t)c*SEL];
    Ssum[g] = s;
}

// ---------------------------------------------------------------------------
// K2 v11: each thread owns TWO j-pairs (j0,j0+1) and (j0+250,j0+251).
// (j+250)%25 == j%25, so the S-row LDS reads are shared between pairs.
// The 96-o loop reads W (3 b128) + (scl,off) b64 ONCE per o and produces
// FOUR outputs (two aligned float2 stores, 250 floats apart) -> dominant
// W-loop LDS stream halved again vs r13. Same FMA order per output.
// ---------------------------------------------------------------------------
__global__ __launch_bounds__(256) void k_out(const float* __restrict__ x,
                                             const float* __restrict__ Ssum,
                                             const float* __restrict__ W,
                                             const float* __restrict__ b,
                                             const float* __restrict__ gamma,
                                             const float* __restrict__ beta,
                                             float* __restrict__ out) {
    const int n = blockIdx.x, tile = blockIdx.y;  // 15 tiles x 20 t
    const int tid = threadIdx.x;

    __shared__ __align__(16) float S_l[3*V_*ROWP];     // 2100
    __shared__ __align__(16) float xsh[TT2*C_*ROWP];   // 1680
    __shared__ __align__(16) float Wl[OUT_*12];        // 1152
    __shared__ __align__(8)  float2 so[OUT_];          // (scl, off) packed

    const float* xn = x + (size_t)n * C_*T_*V_;
    const int t0 = tile * TT2;
    const float inv_bn = rsqrtf(1.0f + 1e-5f);

    for (int i = tid; i < 3*V_*ROWP; i += 256) {
        const int s = i/(V_*ROWP), r = i%(V_*ROWP), v = r/ROWP, u = r%ROWP;
        S_l[i] = (u < V_) ? Ssum[(size_t)n*SEL + s*V_*V_ + v*V_ + u] : 0.f;
    }
    for (int i = tid; i < TT2*C_*ROWP; i += 256) {
        const int tt = i/(C_*ROWP), r = i%(C_*ROWP), c = r/ROWP, u = r%ROWP;
        xsh[i] = (u < V_) ? xn[c*(T_*V_) + (t0+tt)*V_ + u] : 0.f;
    }
    for (int i = tid; i < OUT_*12; i += 256) Wl[i] = W[i];
    if (tid < OUT_) {
        const float sc = gamma[tid] * inv_bn;
        so[tid] = make_float2(sc, b[tid]*sc + beta[tid]);
    }
    __syncthreads();

    if (tid < 125) {
        const int j0 = 2*tid, j1 = j0 + 1;          // pair A
        const int j2 = j0 + 250, j3 = j1 + 250;     // pair B (iv same as A)
        const int tt0 = j0/V_, iv0 = j0%V_;
        const int tt1 = j1/V_, iv1 = j1%V_;
        const int tt2 = tt0 + 10, tt3 = tt1 + 10;   // iv2=iv0, iv3=iv1
        const float* xb0 = &xsh[tt0*C_*ROWP];
        const float* xb1 = &xsh[tt1*C_*ROWP];
        const float* xb2 = &xsh[tt2*C_*ROWP];
        const float* xb3 = &xsh[tt3*C_*ROWP];

        float agg0[12], agg1[12], agg2[12], agg3[12];
        agg0[0] = (float)T_ * xb0[0*ROWP + iv0];
        agg0[1] = (float)T_ * xb0[1*ROWP + iv0];
        agg0[2] = (float)T_ * xb0[2*ROWP + iv0];
        agg1[0] = (float)T_ * xb1[0*ROWP + iv1];
        agg1[1] = (float)T_ * xb1[1*ROWP + iv1];
        agg1[2] = (float)T_ * xb1[2*ROWP + iv1];
        agg2[0] = (float)T_ * xb2[0*ROWP + iv0];
        agg2[1] = (float)T_ * xb2[1*ROWP + iv0];
        agg2[2] = (float)T_ * xb2[2*ROWP + iv0];
        agg3[0] = (float)T_ * xb3[0*ROWP + iv1];
        agg3[1] = (float)T_ * xb3[1*ROWP + iv1];
        agg3[2] = (float)T_ * xb3[2*ROWP + iv1];
        #pragma unroll
        for (int k = 3; k < 12; ++k) { agg0[k]=0.f; agg1[k]=0.f; agg2[k]=0.f; agg3[k]=0.f; }

        const float* Sr[3] = { &S_l[0*V_*ROWP], &S_l[1*V_*ROWP], &S_l[2*V_*ROWP] };
        #pragma unroll
        for (int u4 = 0; u4 < ROWP; u4 += 4) {
            const float4 p0 = *(const float4*)&xb0[0*ROWP + u4];
            const float4 p1 = *(const float4*)&xb0[1*ROWP + u4];
            const float4 p2 = *(const float4*)&xb0[2*ROWP + u4];
            const float4 q0 = *(const float4*)&xb1[0*ROWP + u4];
            const float4 q1 = *(const float4*)&xb1[1*ROWP + u4];
            const float4 q2 = *(const float4*)&xb1[2*ROWP + u4];
            const float4 r0v = *(const float4*)&xb2[0*ROWP + u4];
            const float4 r1v = *(const float4*)&xb2[1*ROWP + u4];
            const float4 r2v = *(const float4*)&xb2[2*ROWP + u4];
            const float4 t0v = *(const float4*)&xb3[0*ROWP + u4];
            const float4 t1v = *(const float4*)&xb3[1*ROWP + u4];
            const float4 t2v = *(const float4*)&xb3[2*ROWP + u4];
            #pragma unroll
            for (int s = 0; s < 3; ++s) {
                const float4 sa = *(const float4*)&Sr[s][iv0*ROWP + u4];
                const float4 sb = *(const float4*)&Sr[s][iv1*ROWP + u4];
                agg0[3*s+3] += sa.x*p0.x + sa.y*p0.y + sa.z*p0.z + sa.w*p0.w;
                agg0[3*s+4] += sa.x*p1.x + sa.y*p1.y + sa.z*p1.z + sa.w*p1.w;
                agg0[3*s+5] += sa.x*p2.x + sa.y*p2.y + sa.z*p2.z + sa.w*p2.w;
                agg1[3*s+3] += sb.x*q0.x + sb.y*q0.y + sb.z*q0.z + sb.w*q0.w;
                agg1[3*s+4] += sb.x*q1.x + sb.y*q1.y + sb.z*q1.z + sb.w*q1.w;
                agg1[3*s+5] += sb.x*q2.x + sb.y*q2.y + sb.z*q2.z + sb.w*q2.w;
                agg2[3*s+3] += sa.x*r0v.x + sa.y*r0v.y + sa.z*r0v.z + sa.w*r0v.w;
                agg2[3*s+4] += sa.x*r1v.x + sa.y*r1v.y + sa.z*r1v.z + sa.w*r1v.w;
                agg2[3*s+5] += sa.x*r2v.x + sa.y*r2v.y + sa.z*r2v.z + sa.w*r2v.w;
                agg3[3*s+3] += sb.x*t0v.x + sb.y*t0v.y + sb.z*t0v.z + sb.w*t0v.w;
                agg3[3*s+4] += sb.x*t1v.x + sb.y*t1v.y + sb.z*t1v.z + sb.w*t1v.w;
                agg3[3*s+5] += sb.x*t2v.x + sb.y*t2v.y + sb.z*t2v.z + sb.w*t2v.w;
            }
        }

        float* onA = out + (size_t)n*(size_t)OUT_*T_*V_ + t0*V_ + j0;
        #pragma unroll 4
        for (int o = 0; o < OUT_; ++o) {
            const float4 w0 = *(const float4*)&Wl[o*12];
            const float4 w1 = *(const float4*)&Wl[o*12+4];
            const float4 w2 = *(const float4*)&Wl[o*12+8];
            const float2 s2 = so[o];
            float a0 = w0.x*agg0[0] + w0.y*agg0[1] + w0.z*agg0[2] + w0.w*agg0[3]
                     + w1.x*agg0[4] + w1.y*agg0[5] + w1.z*agg0[6] + w1.w*agg0[7]
                     + w2.x*agg0[8] + w2.y*agg0[9] + w2.z*agg0[10]+ w2.w*agg0[11];
            float a1 = w0.x*agg1[0] + w0.y*agg1[1] + w0.z*agg1[2] + w0.w*agg1[3]
                     + w1.x*agg1[4] + w1.y*agg1[5] + w1.z*agg1[6] + w1.w*agg1[7]
                     + w2.x*agg1[8] + w2.y*agg1[9] + w2.z*agg1[10]+ w2.w*agg1[11];
            float a2 = w0.x*agg2[0] + w0.y*agg2[1] + w0.z*agg2[2] + w0.w*agg2[3]
                     + w1.x*agg2[4] + w1.y*agg2[5] + w1.z*agg2[6] + w1.w*agg2[7]
                     + w2.x*agg2[8] + w2.y*agg2[9] + w2.z*agg2[10]+ w2.w*agg2[11];
            float a3 = w0.x*agg3[0] + w0.y*agg3[1] + w0.z*agg3[2] + w0.w*agg3[3]
                     + w1.x*agg3[4] + w1.y*agg3[5] + w1.z*agg3[6] + w1.w*agg3[7]
                     + w2.x*agg3[8] + w2.y*agg3[9] + w2.z*agg3[10]+ w2.w*agg3[11];
            float2 rA, rB;
            rA.x = fmaxf(a0*s2.x + s2.y, 0.f);
            rA.y = fmaxf(a1*s2.x + s2.y, 0.f);
            rB.x = fmaxf(a2*s2.x + s2.y, 0.f);
            rB.y = fmaxf(a3*s2.x + s2.y, 0.f);
            float* po = &onA[(size_t)o*(T_*V_)];
            *(float2*)po         = rA;
            *(float2*)(po + 250) = rB;
        }
    }
}

extern "C" void kernel_launch(void* const* d_in, const int* in_sizes, int n_in,
                              void* d_out, int out_size, void* d_ws, size_t ws_size,
                              hipStream_t stream) {
    const float* x     = (const float*)d_in[0];
    const float* xx    = (const float*)d_in[1];
    const float* W     = (const float*)d_in[2];
    const float* b     = (const float*)d_in[3];
    const float* gamma = (const float*)d_in[4];
    const float* beta  = (const float*)d_in[5];
    float* out  = (float*)d_out;

    float* Ssum    = (float*)d_ws;                  // 240 KB
    float* partial = (float*)d_ws + (size_t)N_*SEL; // 14.4 MB (60 recs/n)

    k_powsum<<<dim3(N_, 15), 256, 0, stream>>>(xx, partial);
    k_reduce<<<(N_*SEL + 255)/256, 256, 0, stream>>>(partial, Ssum);
    k_out   <<<dim3(N_, T_/TT2), 256, 0, stream>>>(x, Ssum, W, b, gamma, beta, out);
}

// Round 16
// 58.502 us; speedup vs baseline: 1.7068x; 1.3160x over previous
//
#include <hip/hip_runtime.h>

#define N_   32
#define C_   3
#define T_   300
#define V_   25
#define OUT_ 96
#define ROWP 28              // padded row (float4-aligned)
#define NCH  60              // partial records per n (15 chunks x 4 waves)
#define TT2  20              // t's per k_out block (500 j per block)
#define SEL  (3*V_*V_)       // 1875 floats per sum record

using half8   = __attribute__((ext_vector_type(8))) _Float16;
using floatx4 = __attribute__((ext_vector_type(4))) float;

// ---------------------------------------------------------------------------
// K1 (MFMA): round-11/13 version byte-identical. Measured: 14.2us (r14).
// ---------------------------------------------------------------------------
__global__ __launch_bounds__(256) void k_powsum(const float* __restrict__ xx,
                                                float* __restrict__ partial) {
    const int n = blockIdx.x, chunk = blockIdx.y;   // 15 chunks x 20 t
    const int tid  = threadIdx.x;
    const int wid  = tid >> 6;
    const int lane = tid & 63;
    const int r0   = lane & 15;
    const int kb   = (lane >> 4) * 8;

    __shared__ __align__(16) float xst[4][3][32];
    __shared__ __align__(16) float a2b[4][32][36];

    half8 I0 = {}, I1 = {};
    #pragma unroll
    for (int j = 0; j < 8; ++j) {
        if (kb + j == r0)      I0[j] = (_Float16)1.0f;
        if (kb + j == 16 + r0) I1[j] = (_Float16)1.0f;
    }

    floatx4 acc[3][4];
    #pragma unroll
    for (int s = 0; s < 3; ++s)
        #pragma unroll
        for (int q = 0; q < 4; ++q)
            #pragma unroll
            for (int r = 0; r < 4; ++r) acc[s][q][r] = 0.f;

    const float* xxn = xx + (size_t)n * C_*T_*V_;
    const bool rowOK1 = (r0 < 9);

    for (int tt = 0; tt < 5; ++tt) {
        const int t = chunk*20 + wid*5 + tt;
        {
            const int i0 = lane;
            if (i0 < 75) xst[wid][i0/25][i0%25] = xxn[(i0/25)*(T_*V_) + t*V_ + (i0%25)];
            const int i1 = 64 + lane;
            if (lane < 11) xst[wid][i1/25][i1%25] = xxn[(i1/25)*(T_*V_) + t*V_ + (i1%25)];
        }
        __syncthreads();

        float xr0c[3], xr1c[3], xk[3][8];
        #pragma unroll
        for (int c = 0; c < 3; ++c) {
            xr0c[c] = xst[wid][c][r0];
            xr1c[c] = xst[wid][c][16 + r0];
            const float4 k0 = *(const float4*)&xst[wid][c][kb];
            const float4 k1 = *(const float4*)&xst[wid][c][kb + 4];
            xk[c][0]=k0.x; xk[c][1]=k0.y; xk[c][2]=k0.z; xk[c][3]=k0.w;
            xk[c][4]=k1.x; xk[c][5]=k1.y; xk[c][6]=k1.z; xk[c][7]=k1.w;
        }
        half8 F0, F1;
        #pragma unroll
        for (int j = 0; j < 8; ++j) {
            const int  kk  = kb + j;
            const bool kOK = (kk < 25);
            float d0 = xr0c[0]-xk[0][j], d1 = xr0c[1]-xk[1][j], d2 = xr0c[2]-xk[2][j];
            const float a0 = __expf(-(d0*d0 + d1*d1 + d2*d2));
            F0[j] = kOK ? (_Float16)a0 : (_Float16)0.f;
            float e0 = xr1c[0]-xk[0][j], e1 = xr1c[1]-xk[1][j], e2 = xr1c[2]-xk[2][j];
            const float a1 = __expf(-(e0*e0 + e1*e1 + e2*e2));
            F1[j] = (kOK && rowOK1) ? (_Float16)a1 : (_Float16)0.f;
        }

        const floatx4 z = {0.f, 0.f, 0.f, 0.f};
        floatx4 d2q[4];
        d2q[0] = __builtin_amdgcn_mfma_f32_16x16x32_f16(F0, F0, z, 0, 0, 0);
        d2q[1] = __builtin_amdgcn_mfma_f32_16x16x32_f16(F0, F1, z, 0, 0, 0);
        d2q[2] = __builtin_amdgcn_mfma_f32_16x16x32_f16(F1, F0, z, 0, 0, 0);
        d2q[3] = __builtin_amdgcn_mfma_f32_16x16x32_f16(F1, F1, z, 0, 0, 0);
        acc[0][0] = __builtin_amdgcn_mfma_f32_16x16x32_f16(I0, F0, acc[0][0], 0, 0, 0);
        acc[0][1] = __builtin_amdgcn_mfma_f32_16x16x32_f16(I0, F1, acc[0][1], 0, 0, 0);
        acc[0][2] = __builtin_amdgcn_mfma_f32_16x16x32_f16(I1, F0, acc[0][2], 0, 0, 0);
        acc[0][3] = __builtin_amdgcn_mfma_f32_16x16x32_f16(I1, F1, acc[0][3], 0, 0, 0);
        const int rbase = (lane >> 4) * 4;
        #pragma unroll
        for (int q = 0; q < 4; ++q) {
            #pragma unroll
            for (int r = 0; r < 4; ++r) acc[1][q][r] += d2q[q][r];
            const int RB = 16*(q>>1) + rbase, CC = 16*(q&1) + r0;
            #pragma unroll
            for (int r = 0; r < 4; ++r) a2b[wid][RB + r][CC] = d2q[q][r];
        }
        __syncthreads();

        const float4 m0 = *(const float4*)&a2b[wid][r0][kb];
        const float4 m1 = *(const float4*)&a2b[wid][r0][kb + 4];
        const float4 m2 = *(const float4*)&a2b[wid][16 + r0][kb];
        const float4 m3 = *(const float4*)&a2b[wid][16 + r0][kb + 4];
        half8 FA0, FA1;
        FA0[0]=(_Float16)m0.x; FA0[1]=(_Float16)m0.y; FA0[2]=(_Float16)m0.z; FA0[3]=(_Float16)m0.w;
        FA0[4]=(_Float16)m1.x; FA0[5]=(_Float16)m1.y; FA0[6]=(_Float16)m1.z; FA0[7]=(_Float16)m1.w;
        FA1[0]=(_Float16)m2.x; FA1[1]=(_Float16)m2.y; FA1[2]=(_Float16)m2.z; FA1[3]=(_Float16)m2.w;
        FA1[4]=(_Float16)m3.x; FA1[5]=(_Float16)m3.y; FA1[6]=(_Float16)m3.z; FA1[7]=(_Float16)m3.w;
        acc[2][0] = __builtin_amdgcn_mfma_f32_16x16x32_f16(FA0, F0, acc[2][0], 0, 0, 0);
        acc[2][1] = __builtin_amdgcn_mfma_f32_16x16x32_f16(FA0, F1, acc[2][1], 0, 0, 0);
        acc[2][2] = __builtin_amdgcn_mfma_f32_16x16x32_f16(FA1, F0, acc[2][2], 0, 0, 0);
        acc[2][3] = __builtin_amdgcn_mfma_f32_16x16x32_f16(FA1, F1, acc[2][3], 0, 0, 0);
        __syncthreads();
    }

    float* pb = partial + ((size_t)n*NCH + chunk*4 + wid) * SEL;
    const int rbase = (lane >> 4) * 4;
    #pragma unroll
    for (int s = 0; s < 3; ++s) {
        #pragma unroll
        for (int q = 0; q < 4; ++q) {
            const int RB = 16*(q>>1) + rbase, CC = 16*(q&1) + r0;
            #pragma unroll
            for (int r = 0; r < 4; ++r) a2b[wid][RB + r][CC] = acc[s][q][r];
        }
        __syncthreads();
        for (int i = lane; i < V_*V_; i += 64)
            pb[s*V_*V_ + i] = a2b[wid][i/V_][i%V_];
        __syncthreads();
    }
}

// ---------------------------------------------------------------------------
// K1b: byte-identical r13.
// ---------------------------------------------------------------------------
__global__ __launch_bounds__(256) void k_reduce(const float* __restrict__ partial,
                                                float* __restrict__ Ssum) {
    const int g = blockIdx.x*256 + threadIdx.x;
    if (g >= N_*SEL) return;
    const int n = g / SEL, j = g % SEL;
    const float* p = partial + (size_t)n*NCH*SEL + j;
    float s = 0.f;
    #pragma unroll
    for (int c = 0; c < NCH; ++c) s += p[(size_t)c*SEL];
    Ssum[g] = s;
}

// ---------------------------------------------------------------------------
// K2 v12: r13 structure (j-pair, 250 threads, float2 stores) EXCEPT the
// o-loop reads W from GLOBAL with loop-uniform address in groups of 4 o's
// (12 batched s_load_dwordx4 -> SMEM pipe, one waitcnt per group) instead of
// 3 ds_read_b128 per o. Removes the ~12.5us/CU LDS broadcast stream (r6's
// failure was per-o un-batched loads). so[] (scl,off) stays in LDS (b64).
// ---------------------------------------------------------------------------
__global__ __launch_bounds__(256) void k_out(const float* __restrict__ x,
                                             const float* __restrict__ Ssum,
                                             const float* __restrict__ W,
                                             const float* __restrict__ b,
                                             const float* __restrict__ gamma,
                                             const float* __restrict__ beta,
                                             float* __restrict__ out) {
    const int n = blockIdx.x, tile = blockIdx.y;  // 15 tiles x 20 t
    const int tid = threadIdx.x;

    __shared__ __align__(16) float S_l[3*V_*ROWP];     // 2100
    __shared__ __align__(16) float xsh[TT2*C_*ROWP];   // 1680
    __shared__ __align__(8)  float2 so[OUT_];          // (scl, off)

    const float* xn = x + (size_t)n * C_*T_*V_;
    const int t0 = tile * TT2;
    const float inv_bn = rsqrtf(1.0f + 1e-5f);

    for (int i = tid; i < 3*V_*ROWP; i += 256) {
        const int s = i/(V_*ROWP), r = i%(V_*ROWP), v = r/ROWP, u = r%ROWP;
        S_l[i] = (u < V_) ? Ssum[(size_t)n*SEL + s*V_*V_ + v*V_ + u] : 0.f;
    }
    for (int i = tid; i < TT2*C_*ROWP; i += 256) {
        const int tt = i/(C_*ROWP), r = i%(C_*ROWP), c = r/ROWP, u = r%ROWP;
        xsh[i] = (u < V_) ? xn[c*(T_*V_) + (t0+tt)*V_ + u] : 0.f;
    }
    if (tid < OUT_) {
        const float sc = gamma[tid] * inv_bn;
        so[tid] = make_float2(sc, b[tid]*sc + beta[tid]);
    }
    __syncthreads();

    if (tid < TT2*V_/2) {
        const int j0 = 2*tid, j1 = 2*tid + 1;
        const int tt0 = j0 / V_, iv0 = j0 % V_;
        const int tt1 = j1 / V_, iv1 = j1 % V_;
        const float* xb0 = &xsh[tt0*C_*ROWP];
        const float* xb1 = &xsh[tt1*C_*ROWP];

        float agg0[12], agg1[12];
        agg0[0] = (float)T_ * xb0[0*ROWP + iv0];
        agg0[1] = (float)T_ * xb0[1*ROWP + iv0];
        agg0[2] = (float)T_ * xb0[2*ROWP + iv0];
        agg1[0] = (float)T_ * xb1[0*ROWP + iv1];
        agg1[1] = (float)T_ * xb1[1*ROWP + iv1];
        agg1[2] = (float)T_ * xb1[2*ROWP + iv1];
        #pragma unroll
        for (int k = 3; k < 12; ++k) { agg0[k] = 0.f; agg1[k] = 0.f; }

        const float* Sr[3] = { &S_l[0*V_*ROWP], &S_l[1*V_*ROWP], &S_l[2*V_*ROWP] };
        #pragma unroll
        for (int u4 = 0; u4 < ROWP; u4 += 4) {
            const float4 p0 = *(const float4*)&xb0[0*ROWP + u4];
            const float4 p1 = *(const float4*)&xb0[1*ROWP + u4];
            const float4 p2 = *(const float4*)&xb0[2*ROWP + u4];
            const float4 q0 = *(const float4*)&xb1[0*ROWP + u4];
            const float4 q1 = *(const float4*)&xb1[1*ROWP + u4];
            const float4 q2 = *(const float4*)&xb1[2*ROWP + u4];
            #pragma unroll
            for (int s = 0; s < 3; ++s) {
                const float4 sa = *(const float4*)&Sr[s][iv0*ROWP + u4];
                const float4 sb = *(const float4*)&Sr[s][iv1*ROWP + u4];
                agg0[3*s+3] += sa.x*p0.x + sa.y*p0.y + sa.z*p0.z + sa.w*p0.w;
                agg0[3*s+4] += sa.x*p1.x + sa.y*p1.y + sa.z*p1.z + sa.w*p1.w;
                agg0[3*s+5] += sa.x*p2.x + sa.y*p2.y + sa.z*p2.z + sa.w*p2.w;
                agg1[3*s+3] += sb.x*q0.x + sb.y*q0.y + sb.z*q0.z + sb.w*q0.w;
                agg1[3*s+4] += sb.x*q1.x + sb.y*q1.y + sb.z*q1.z + sb.w*q1.w;
                agg1[3*s+5] += sb.x*q2.x + sb.y*q2.y + sb.z*q2.z + sb.w*q2.w;
            }
        }

        float* on = out + (size_t)n*(size_t)OUT_*T_*V_ + t0*V_ + j0;

        #define DOT2(AG0, AG1, w0_, w1_, w2_, s2_, OO)                          \
        {   float a0 = (w0_).x*AG0[0] + (w0_).y*AG0[1] + (w0_).z*AG0[2] + (w0_).w*AG0[3] \
                     + (w1_).x*AG0[4] + (w1_).y*AG0[5] + (w1_).z*AG0[6] + (w1_).w*AG0[7] \
                     + (w2_).x*AG0[8] + (w2_).y*AG0[9] + (w2_).z*AG0[10]+ (w2_).w*AG0[11]; \
            float a1 = (w0_).x*AG1[0] + (w0_).y*AG1[1] + (w0_).z*AG1[2] + (w0_).w*AG1[3] \
                     + (w1_).x*AG1[4] + (w1_).y*AG1[5] + (w1_).z*AG1[6] + (w1_).w*AG1[7] \
                     + (w2_).x*AG1[8] + (w2_).y*AG1[9] + (w2_).z*AG1[10]+ (w2_).w*AG1[11]; \
            float2 r_;                                                          \
            r_.x = fmaxf(a0*(s2_).x + (s2_).y, 0.f);                            \
            r_.y = fmaxf(a1*(s2_).x + (s2_).y, 0.f);                            \
            *(float2*)&on[(size_t)(OO)*(T_*V_)] = r_;                           \
        }

        for (int og = 0; og < OUT_; og += 4) {
            // 12 batched uniform loads (SMEM/K$); one waitcnt covers all.
            const float4 wa0 = *(const float4*)&W[og*12 +  0];
            const float4 wa1 = *(const float4*)&W[og*12 +  4];
            const float4 wa2 = *(const float4*)&W[og*12 +  8];
            const float4 wb0 = *(const float4*)&W[og*12 + 12];
            const float4 wb1 = *(const float4*)&W[og*12 + 16];
            const float4 wb2 = *(const float4*)&W[og*12 + 20];
            const float4 wc0 = *(const float4*)&W[og*12 + 24];
            const float4 wc1 = *(const float4*)&W[og*12 + 28];
            const float4 wc2 = *(const float4*)&W[og*12 + 32];
            const float4 wd0 = *(const float4*)&W[og*12 + 36];
            const float4 wd1 = *(const float4*)&W[og*12 + 40];
            const float4 wd2 = *(const float4*)&W[og*12 + 44];
            const float2 sA = so[og+0], sB = so[og+1], sC = so[og+2], sD = so[og+3];
            DOT2(agg0, agg1, wa0, wa1, wa2, sA, og+0);
            DOT2(agg0, agg1, wb0, wb1, wb2, sB, og+1);
            DOT2(agg0, agg1, wc0, wc1, wc2, sC, og+2);
            DOT2(agg0, agg1, wd0, wd1, wd2, sD, og+3);
        }
        #undef DOT2
    }
}

extern "C" void kernel_launch(void* const* d_in, const int* in_sizes, int n_in,
                              void* d_out, int out_size, void* d_ws, size_t ws_size,
                              hipStream_t stream) {
    const float* x     = (const float*)d_in[0];
    const float* xx    = (const float*)d_in[1];
    const float* W     = (const float*)d_in[2];
    const float* b     = (const float*)d_in[3];
    const float* gamma = (const float*)d_in[4];
    const float* beta  = (const float*)d_in[5];
    float* out  = (float*)d_out;

    float* Ssum    = (float*)d_ws;                  // 240 KB
    float* partial = (float*)d_ws + (size_t)N_*SEL; // 14.4 MB (60 recs/n)

    k_powsum<<<dim3(N_, 15), 256, 0, stream>>>(xx, partial);
    k_reduce<<<(N_*SEL + 255)/256, 256, 0, stream>>>(partial, Ssum);
    k_out   <<<dim3(N_, T_/TT2), 256, 0, stream>>>(x, Ssum, W, b, gamma, beta, out);
}